// Round 8
// baseline (678.438 us; speedup 1.0000x reference)
//
#include <hip/hip_runtime.h>
#include <cstdint>

typedef unsigned int u32;
typedef unsigned long long u64;
typedef _Float16 f16;
typedef f16 f16x8 __attribute__((ext_vector_type(8)));
typedef f16 f16x4 __attribute__((ext_vector_type(4)));
typedef float f32x4 __attribute__((ext_vector_type(4)));

#define R_ROIS 2000
#define CIN 12544
#define HID 1024
#define NCLS 80
#define NHEAD 401
#define RC (R_ROIS*NCLS)       // 160000
#define KTOP 1000
#define IMTOP 100
#define KEY_NEG1 0x407FFFFFu   // fkey(-1.0f)
#define BBOX_CLIPV 4.135166556742356f
#define NCHUNK 157             // ceil(160000/1024)

__device__ __forceinline__ u32 fkey(float f) {
  u32 u = __float_as_uint(f);
  return (u & 0x80000000u) ? ~u : (u | 0x80000000u);
}
__device__ __forceinline__ float fkeyinv(u32 k) {
  u32 b = (k & 0x80000000u) ? (k & 0x7FFFFFFFu) : ~k;
  return __uint_as_float(b);
}
__device__ __forceinline__ u32 mkey(const u32* keys, const int* imidx, int i, int g) {
  int r = i / NCLS;
  return (imidx[r] == g) ? keys[i] : KEY_NEG1;
}

__device__ __forceinline__ void lds16(const f16* gsrc, f16* ldst) {
  __builtin_amdgcn_global_load_lds(
      (const __attribute__((address_space(1))) void*)gsrc,
      (__attribute__((address_space(3))) void*)ldst, 16, 0, 0);
}

// ================= fp16-split MFMA GEMM, 2-phase prefetch, 8 waves =================
// C[M,N] += sum_k (A1+A2)[m,k]*(B1+B2)[n,k] ~= A1B1 + A1B2 + A2B1.
// NT layout, K pitch = K. 128x128 tile, BK=32, 8 waves (2x4 of 64x32),
// mfma_f32_16x16x32_f16, splitK via f32 atomicAdd into (bias-)prefilled C.
// 512 threads, __launch_bounds__(512,4): 2 blocks/CU x 8 waves = 16 waves/CU
// (round-7 showed 2.6 TB/s fetch path at 8 waves/CU is the limiter; this
// doubles memory-latency-hiding concurrency at identical traffic).
// LDS double-buffered (64 KiB); next tile staged via global_load_lds BEFORE
// compute of current tile; raw s_barrier + manual vmcnt(0).
// LDS bank swizzle (verified round-7: conflicts 12.8M -> 0): 16B-seg col j
// stored at j ^ ((row>>1)&3) via swizzled GLOBAL source (linear LDS dest),
// mirrored on ds_read -> register contents identical to unswizzled.
__global__ __launch_bounds__(512, 4)
void gemm_f16x3(const f16* __restrict__ A1, const f16* __restrict__ A2,
                const f16* __restrict__ B1, const f16* __restrict__ B2,
                float* __restrict__ C, int M, int N, int K, int kLen)
{
  __shared__ __align__(16) f16 As1[2][128 * 32];
  __shared__ __align__(16) f16 As2[2][128 * 32];
  __shared__ __align__(16) f16 Bs1[2][128 * 32];
  __shared__ __align__(16) f16 Bs2[2][128 * 32];

  int t = threadIdx.x;
  int w = t >> 6, lane = t & 63;
  int wm = w >> 2, wn = w & 3;        // 2 x 4 wave grid; wave tile 64(M) x 32(N)
  int m0 = blockIdx.y * 128, n0 = blockIdx.x * 128;
  int k0 = blockIdx.z * kLen;

  f32x4 acc[4][2];
#pragma unroll
  for (int mi = 0; mi < 4; ++mi)
#pragma unroll
    for (int ni = 0; ni < 2; ++ni)
#pragma unroll
      for (int r = 0; r < 4; ++r) acc[mi][ni][r] = 0.f;

  // staging: 512 segs of 16B per tile; thread t covers seg t (1 per array).
  // global source col-seg XOR-swizzled so linear LDS slot (row,j) holds
  // data seg (row, j ^ ((row>>1)&3)).
  int row0 = t >> 2;       int j0 = (t & 3) ^ ((row0 >> 1) & 3);
  int rmA0 = m0 + row0; if (rmA0 > M - 1) rmA0 = M - 1;
  int rnB0 = n0 + row0; if (rnB0 > N - 1) rnB0 = N - 1;
  size_t a0 = (size_t)rmA0 * K + j0 * 8;
  size_t b0 = (size_t)rnB0 * K + j0 * 8;
  int sw0 = (w * 64) * 8;          // wave-uniform LDS base (elements)

  int rrow = lane & 15;
  int cxor = (rrow >> 1) & 3;                  // (row>>1)&3 within tile
  int rsel = ((lane >> 4) ^ cxor) * 8;         // swizzled 16B-seg on read

  int nt = kLen / 32;
  // prologue: stage tile 0 into buf 0
  {
    int kb = k0;
    lds16(A1 + a0 + kb, &As1[0][sw0]);
    lds16(A2 + a0 + kb, &As2[0][sw0]);
    lds16(B1 + b0 + kb, &Bs1[0][sw0]);
    lds16(B2 + b0 + kb, &Bs2[0][sw0]);
  }
  asm volatile("s_waitcnt vmcnt(0)" ::: "memory");
  __builtin_amdgcn_s_barrier();
  __builtin_amdgcn_sched_barrier(0);

  int cur = 0;
  for (int tt = 0; tt < nt; ++tt) {
    if (tt + 1 < nt) {                 // issue next-tile loads first (overlap)
      int kb = k0 + (tt + 1) * 32;
      int nx = cur ^ 1;
      lds16(A1 + a0 + kb, &As1[nx][sw0]);
      lds16(A2 + a0 + kb, &As2[nx][sw0]);
      lds16(B1 + b0 + kb, &Bs1[nx][sw0]);
      lds16(B2 + b0 + kb, &Bs2[nx][sw0]);
    }
    __builtin_amdgcn_sched_barrier(0);

    f16x8 af1[4], af2[4], bf1[2], bf2[2];
#pragma unroll
    for (int mi = 0; mi < 4; ++mi) {
      int ra = (wm * 64 + mi * 16 + rrow) * 32 + rsel;
      af1[mi] = *(const f16x8*)&As1[cur][ra];
      af2[mi] = *(const f16x8*)&As2[cur][ra];
    }
#pragma unroll
    for (int ni = 0; ni < 2; ++ni) {
      int rb = (wn * 32 + ni * 16 + rrow) * 32 + rsel;
      bf1[ni] = *(const f16x8*)&Bs1[cur][rb];
      bf2[ni] = *(const f16x8*)&Bs2[cur][rb];
    }
    __builtin_amdgcn_s_setprio(1);
#pragma unroll
    for (int mi = 0; mi < 4; ++mi)
#pragma unroll
      for (int ni = 0; ni < 2; ++ni) {
        acc[mi][ni] = __builtin_amdgcn_mfma_f32_16x16x32_f16(af1[mi], bf1[ni], acc[mi][ni], 0, 0, 0);
        acc[mi][ni] = __builtin_amdgcn_mfma_f32_16x16x32_f16(af1[mi], bf2[ni], acc[mi][ni], 0, 0, 0);
        acc[mi][ni] = __builtin_amdgcn_mfma_f32_16x16x32_f16(af2[mi], bf1[ni], acc[mi][ni], 0, 0, 0);
      }
    __builtin_amdgcn_s_setprio(0);
    __builtin_amdgcn_sched_barrier(0);
    asm volatile("s_waitcnt vmcnt(0)" ::: "memory");   // next-tile stage landed
    __builtin_amdgcn_s_barrier();
    __builtin_amdgcn_sched_barrier(0);
    cur ^= 1;
  }

  // epilogue: C/D layout col=lane&15, row=(lane>>4)*4+r (m89-verified)
  int crow = m0 + wm * 64 + (lane >> 4) * 4;
  int ccol = n0 + wn * 32 + (lane & 15);
#pragma unroll
  for (int mi = 0; mi < 4; ++mi)
#pragma unroll
    for (int r = 0; r < 4; ++r) {
      int rm = crow + mi * 16 + r;
      if (rm < M) {
#pragma unroll
        for (int ni = 0; ni < 2; ++ni) {
          int cc = ccol + ni * 16;
          if (cc < N) atomicAdd(&C[(size_t)rm * N + cc], acc[mi][ni][r]);
        }
      }
    }
}

// fused split of roi / fc1_w / fc2_w into fp16 (hi, lo) pairs; counts in float4
__global__ void split3_k(const float* __restrict__ s0, int c0,
                         const float* __restrict__ s1, int c1,
                         const float* __restrict__ s2, int c2,
                         f16* __restrict__ d0a, f16* __restrict__ d0b,
                         f16* __restrict__ d1a, f16* __restrict__ d1b,
                         f16* __restrict__ d2a, f16* __restrict__ d2b)
{
  int total = c0 + c1 + c2;
  for (int i = blockIdx.x * blockDim.x + threadIdx.x; i < total; i += gridDim.x * blockDim.x) {
    const float* src; f16 *da, *db; int j;
    if (i < c0) { src = s0; da = d0a; db = d0b; j = i; }
    else if (i < c0 + c1) { src = s1; da = d1a; db = d1b; j = i - c0; }
    else { src = s2; da = d2a; db = d2b; j = i - c0 - c1; }
    float4 v = ((const float4*)src)[j];
    f16x4 o1, o2;
    o1[0] = (f16)v.x; o2[0] = (f16)(v.x - (float)o1[0]);
    o1[1] = (f16)v.y; o2[1] = (f16)(v.y - (float)o1[1]);
    o1[2] = (f16)v.z; o2[2] = (f16)(v.z - (float)o1[2]);
    o1[3] = (f16)v.w; o2[3] = (f16)(v.w - (float)o1[3]);
    ((f16x4*)da)[j] = o1;
    ((f16x4*)db)[j] = o2;
  }
}

// pack [cls_w;reg_w] into 512-row fp16 split (rows >=401 clamp to 400)
__global__ void packhead_k(const float* __restrict__ clsw, const float* __restrict__ regw,
                           f16* __restrict__ W1, f16* __restrict__ W2)
{
  int i = blockIdx.x * blockDim.x + threadIdx.x;   // float4 index over 512*256
  if (i >= 512 * 256) return;
  int r = i >> 8, c4 = i & 255;
  int rr = (r < NHEAD) ? r : (NHEAD - 1);
  const float* src = (rr < 81) ? (clsw + (size_t)rr * HID) : (regw + (size_t)(rr - 81) * HID);
  float4 v = ((const float4*)src)[c4];
  f16x4 o1, o2;
  o1[0] = (f16)v.x; o2[0] = (f16)(v.x - (float)o1[0]);
  o1[1] = (f16)v.y; o2[1] = (f16)(v.y - (float)o1[1]);
  o1[2] = (f16)v.z; o2[2] = (f16)(v.z - (float)o1[2]);
  o1[3] = (f16)v.w; o2[3] = (f16)(v.w - (float)o1[3]);
  ((f16x4*)W1)[i] = o1;
  ((f16x4*)W2)[i] = o2;
}

// prefill HEADS with bias (heads gemm atomicAdds on top)
__global__ void biasfill_k(const float* __restrict__ clsb, const float* __restrict__ regb,
                           float* __restrict__ H)
{
  int i = blockIdx.x * blockDim.x + threadIdx.x;
  if (i >= R_ROIS * NHEAD) return;
  int c = i % NHEAD;
  H[i] = (c < 81) ? clsb[c] : regb[c - 81];
}

// bias+relu on f32 activations, emit fp16 split
__global__ void bias_relu_split_k(const float* __restrict__ X, const float* __restrict__ bias,
                                  f16* __restrict__ H1, f16* __restrict__ H2, int total)
{
  int i = blockIdx.x * blockDim.x + threadIdx.x;
  if (i >= total) return;
  float v = fmaxf(X[i] + bias[i & (HID - 1)], 0.f);
  f16 a = (f16)v;
  H1[i] = a;
  H2[i] = (f16)(v - (float)a);
}

// ---------------- f32 GEMM (fallback path) ----------------
__global__ __launch_bounds__(256, 2)
void gemm128(const float* __restrict__ A, int lda,
             const float* __restrict__ B, int ldb,
             float* __restrict__ C, int M, int N, int kLen)
{
  __shared__ float As[128][20];
  __shared__ float Bs[128][20];
  int t = threadIdx.x;
  int tx = t & 15, ty = t >> 4;
  int m0 = blockIdx.y * 128, n0 = blockIdx.x * 128;
  int k0 = blockIdx.z * kLen;
  float acc[8][8];
#pragma unroll
  for (int i = 0; i < 8; ++i)
#pragma unroll
    for (int j = 0; j < 8; ++j) acc[i][j] = 0.f;

  int lr = t >> 2;
  int lk = (t & 3) * 4;

  for (int ks = 0; ks < kLen; ks += 16) {
#pragma unroll
    for (int p = 0; p < 2; ++p) {
      int row = lr + p * 64;
      int rm = m0 + row; if (rm > M - 1) rm = M - 1;
      float4 av = *(const float4*)(A + (size_t)rm * lda + k0 + ks + lk);
      *(float4*)&As[row][lk] = av;
      int rn = n0 + row; if (rn > N - 1) rn = N - 1;
      float4 bv = *(const float4*)(B + (size_t)rn * ldb + k0 + ks + lk);
      *(float4*)&Bs[row][lk] = bv;
    }
    __syncthreads();
#pragma unroll
    for (int kk = 0; kk < 16; kk += 4) {
      float4 a4[8], b4[8];
#pragma unroll
      for (int i = 0; i < 8; ++i) a4[i] = *(const float4*)&As[ty + (i << 4)][kk];
#pragma unroll
      for (int j = 0; j < 8; ++j) b4[j] = *(const float4*)&Bs[tx + (j << 4)][kk];
#pragma unroll
      for (int i = 0; i < 8; ++i)
#pragma unroll
        for (int j = 0; j < 8; ++j) {
          acc[i][j] += a4[i].x * b4[j].x;
          acc[i][j] += a4[i].y * b4[j].y;
          acc[i][j] += a4[i].z * b4[j].z;
          acc[i][j] += a4[i].w * b4[j].w;
        }
    }
    __syncthreads();
  }
#pragma unroll
  for (int i = 0; i < 8; ++i) {
    int rm = m0 + ty + (i << 4);
    if (rm < M) {
#pragma unroll
      for (int j = 0; j < 8; ++j) {
        int rn = n0 + tx + (j << 4);
        atomicAdd(&C[(size_t)rm * N + rn], acc[i][j]);
      }
    }
  }
}

__global__ void bias_relu_k(float* __restrict__ X, const float* __restrict__ bias, int total4)
{
  int i4 = blockIdx.x * blockDim.x + threadIdx.x;
  if (i4 >= total4) return;
  int c4 = i4 & 255;
  float4 v = ((float4*)X)[i4];
  float4 b = ((const float4*)bias)[c4];
  v.x = fmaxf(v.x + b.x, 0.f);
  v.y = fmaxf(v.y + b.y, 0.f);
  v.z = fmaxf(v.z + b.z, 0.f);
  v.w = fmaxf(v.w + b.w, 0.f);
  ((float4*)X)[i4] = v;
}

// ---------------- heads (fallback f32): H[2000][401] = A @ [cls_w;reg_w]^T + bias
__global__ __launch_bounds__(256)
void gemm_heads(const float* __restrict__ A,
                const float* __restrict__ clsw, const float* __restrict__ clsb,
                const float* __restrict__ regw, const float* __restrict__ regb,
                float* __restrict__ H)
{
  __shared__ float As[64][36];
  __shared__ float Bs[64][36];
  int t = threadIdx.x;
  int tx = t & 15, ty = t >> 4;
  int m0 = blockIdx.y * 64, n0 = blockIdx.x * 64;
  float acc[4][4] = {};
  int lr = t >> 3;
  int lk = (t & 7) * 4;

  for (int ks = 0; ks < HID; ks += 32) {
#pragma unroll
    for (int p = 0; p < 2; ++p) {
      int row = lr + p * 32;
      int rm = m0 + row; if (rm > R_ROIS - 1) rm = R_ROIS - 1;
      *(float4*)&As[row][lk] = *(const float4*)(A + (size_t)rm * HID + ks + lk);
      int rn = n0 + row; if (rn > NHEAD - 1) rn = NHEAD - 1;
      const float* bp = (rn < 81) ? (clsw + (size_t)rn * HID) : (regw + (size_t)(rn - 81) * HID);
      *(float4*)&Bs[row][lk] = *(const float4*)(bp + ks + lk);
    }
    __syncthreads();
#pragma unroll
    for (int kk = 0; kk < 32; kk += 4) {
      float4 a4[4], b4[4];
#pragma unroll
      for (int i = 0; i < 4; ++i) a4[i] = *(const float4*)&As[ty + (i << 4)][kk];
#pragma unroll
      for (int j = 0; j < 4; ++j) b4[j] = *(const float4*)&Bs[tx + (j << 4)][kk];
#pragma unroll
      for (int i = 0; i < 4; ++i)
#pragma unroll
        for (int j = 0; j < 4; ++j) {
          acc[i][j] += a4[i].x * b4[j].x;
          acc[i][j] += a4[i].y * b4[j].y;
          acc[i][j] += a4[i].z * b4[j].z;
          acc[i][j] += a4[i].w * b4[j].w;
        }
    }
    __syncthreads();
  }
#pragma unroll
  for (int i = 0; i < 4; ++i) {
    int rm = m0 + ty + (i << 4);
#pragma unroll
    for (int j = 0; j < 4; ++j) {
      int rn = n0 + tx + (j << 4);
      if (rm < R_ROIS && rn < NHEAD) {
        float b = (rn < 81) ? clsb[rn] : regb[rn - 81];
        H[(size_t)rm * NHEAD + rn] = acc[i][j] + b;
      }
    }
  }
}

// ---------------- softmax + box decode + mask; one wave per roi
__global__ __launch_bounds__(256)
void decode_k(const float* __restrict__ H, const float* __restrict__ prop,
              const int* __restrict__ imidx, const float* __restrict__ imsz,
              u32* __restrict__ keys, float* __restrict__ boxes)
{
  int lane = threadIdx.x & 63;
  int r = blockIdx.x * 4 + (threadIdx.x >> 6);
  const float* h = H + (size_t)r * NHEAD;
  float l0 = h[lane];
  float l1 = (lane < 17) ? h[64 + lane] : -1e30f;
  float mx = fmaxf(l0, l1);
#pragma unroll
  for (int o = 32; o; o >>= 1) mx = fmaxf(mx, __shfl_xor(mx, o));
  float e0 = expf(l0 - mx);
  float e1 = (lane < 17) ? expf(l1 - mx) : 0.f;
  float s = e0 + e1;
#pragma unroll
  for (int o = 32; o; o >>= 1) s += __shfl_xor(s, o);

  float px1 = prop[r * 4 + 0], py1 = prop[r * 4 + 1];
  float px2 = prop[r * 4 + 2], py2 = prop[r * 4 + 3];
  float pw = px2 - px1, ph = py2 - py1;
  float pcx = px1 + 0.5f * pw, pcy = py1 + 0.5f * ph;
  int g = imidx[r];
  float imh = imsz[g * 2 + 0], imw = imsz[g * 2 + 1];

#pragma unroll
  for (int q = 0; q < 2; ++q) {
    int c = (q == 0) ? lane : 64 + lane;
    bool on = (q == 0) ? true : (lane < 16);
    if (on) {
      float e = (q == 0) ? e0 : e1;
      float scr = e / s;
      const float* rg = h + 81 + c * 4;
      float dx = rg[0] * 0.1f, dy = rg[1] * 0.1f;
      float dw = fminf(rg[2] * 0.2f, BBOX_CLIPV);
      float dh = fminf(rg[3] * 0.2f, BBOX_CLIPV);
      float cx = dx * pw + pcx, cy = dy * ph + pcy;
      float w = expf(dw) * pw, hh = expf(dh) * ph;
      float x1 = cx - 0.5f * w, y1 = cy - 0.5f * hh;
      float x2 = cx + 0.5f * w, y2 = cy + 0.5f * hh;
      x1 = fminf(fmaxf(x1, 0.f), imw);
      x2 = fminf(fmaxf(x2, 0.f), imw);
      y1 = fminf(fmaxf(y1, 0.f), imh);
      y2 = fminf(fmaxf(y2, 0.f), imh);
      float bw = x2 - x1, bh = y2 - y1;
      bool msk = (scr > 0.05f) && (bw >= 1.f) && (bh >= 1.f);
      float sm = msk ? scr : -1.f;
      int idx = r * 80 + c;
      keys[idx] = fkey(sm);
      ((float4*)boxes)[idx] = make_float4(x1, y1, x2, y2);
    }
  }
}

// ---------------- exact rank-1000 threshold: 3-level radix histogram refine
__global__ void hist_k(const u32* __restrict__ keys, const int* __restrict__ imidx,
                       const u32* __restrict__ sel, u32* __restrict__ hist, int level, int nbins)
{
  __shared__ u32 lh[2048];
  int t = threadIdx.x, g = blockIdx.y;
  for (int b = t; b < 2048; b += 256) lh[b] = 0;
  __syncthreads();
  u32 b1 = 0, pre21 = 0;
  if (level == 2) b1 = sel[g * 8 + 0];
  if (level == 3) pre21 = (sel[g * 8 + 0] << 11) | sel[g * 8 + 1];
  for (int i = blockIdx.x * 256 + t; i < RC; i += gridDim.x * 256) {
    u32 k = mkey(keys, imidx, i, g);
    if (level == 1) atomicAdd(&lh[k >> 21], 1u);
    else if (level == 2) { if ((k >> 21) == b1) atomicAdd(&lh[(k >> 10) & 0x7FFu], 1u); }
    else { if ((k >> 10) == pre21) atomicAdd(&lh[k & 0x3FFu], 1u); }
  }
  __syncthreads();
  for (int b = t; b < nbins; b += 256) { u32 v = lh[b]; if (v) atomicAdd(&hist[g * nbins + b], v); }
}

__global__ void find_k(const u32* __restrict__ hist, int nbins, u32* __restrict__ sel, int level)
{
  __shared__ u32 sh[256];
  int t = threadIdx.x, g = blockIdx.x;
  int per = nbins >> 8;
  const u32* h = hist + g * nbins;
  u32 mySum = 0;
  for (int jj = 0; jj < per; ++jj) mySum += h[t * per + jj];
  u32 base = (level == 1) ? 0u : sel[g * 8 + 3];
  sh[t] = mySum; __syncthreads();
  for (int off = 1; off < 256; off <<= 1) {
    u32 v = (t + off < 256) ? sh[t + off] : 0u; __syncthreads();
    sh[t] += v; __syncthreads();
  }
  u32 c = base + ((t < 255) ? sh[t + 1] : 0u);
  for (int jj = per - 1; jj >= 0; --jj) {
    int b = t * per + jj;
    u32 cnt = h[b];
    if (c < KTOP && c + cnt >= KTOP) {
      if (level == 1) { sel[g * 8 + 0] = (u32)b; sel[g * 8 + 3] = c; }
      else if (level == 2) { sel[g * 8 + 1] = (u32)b; sel[g * 8 + 3] = c; }
      else {
        u32 T = (sel[g * 8 + 0] << 21) | (sel[g * 8 + 1] << 10) | (u32)b;
        sel[g * 8 + 4] = T; sel[g * 8 + 3] = c; sel[g * 8 + 5] = KTOP - c;
      }
    }
    c += cnt;
  }
}

// ---------------- stable selection of ties at T (ascending flat index), then compact
__global__ void eqcount_k(const u32* __restrict__ keys, const int* __restrict__ imidx,
                          const u32* __restrict__ sel, u32* __restrict__ eqcnt)
{
  int g = blockIdx.y, t = threadIdx.x;
  int i = blockIdx.x * 1024 + t;
  u32 T = sel[g * 8 + 4];
  bool eq = (i < RC) && (mkey(keys, imidx, i, g) == T);
  u64 bal = __ballot(eq);
  __shared__ u32 wc[16];
  if ((t & 63) == 0) wc[t >> 6] = (u32)__popcll(bal);
  __syncthreads();
  if (t == 0) {
    u32 sum = 0;
    for (int w = 0; w < 16; ++w) sum += wc[w];
    eqcnt[g * 160 + blockIdx.x] = sum;
  }
}

__global__ void eqscan_k(const u32* __restrict__ eqcnt, u32* __restrict__ eqoff)
{
  __shared__ u32 sh[256];
  int t = threadIdx.x, g = blockIdx.x;
  u32 v = (t < NCHUNK) ? eqcnt[g * 160 + t] : 0u;
  sh[t] = v; __syncthreads();
  for (int off = 1; off < 256; off <<= 1) {
    u32 u = (t >= off) ? sh[t - off] : 0u; __syncthreads();
    sh[t] += u; __syncthreads();
  }
  if (t < NCHUNK) eqoff[g * 160 + t] = sh[t] - v;
}

__global__ void emit_k(const u32* __restrict__ keys, const int* __restrict__ imidx,
                       const u32* __restrict__ sel, const u32* __restrict__ eqoff,
                       u32* __restrict__ cntgt, u32* __restrict__ cand)
{
  int g = blockIdx.y, t = threadIdx.x;
  int i = blockIdx.x * 1024 + t;
  u32 T = sel[g * 8 + 4], m = sel[g * 8 + 5], ra = sel[g * 8 + 3];
  u32 k = (i < RC) ? mkey(keys, imidx, i, g) : 0u;
  if (k > T) { u32 p = atomicAdd(&cntgt[g], 1u); cand[g * 1024 + p] = (u32)i; }
  bool eq = (k == T);
  u64 bal = __ballot(eq);
  int w = t >> 6, lane = t & 63;
  __shared__ u32 wc[16];
  if (lane == 0) wc[w] = (u32)__popcll(bal);
  __syncthreads();
  u32 wb = 0;
  for (int x = 0; x < w; ++x) wb += wc[x];
  if (eq) {
    u32 lanePre = (u32)__popcll(bal & ((1ull << lane) - 1ull));
    u32 rank = eqoff[g * 160 + blockIdx.x] + wb + lanePre;
    if (rank < m) cand[g * 1024 + ra + rank] = (u32)i;
  }
}

// ---------------- bitonic sort of 1000 (pad 1024): key desc, idx asc
__global__ __launch_bounds__(512)
void sort_k(const u32* __restrict__ cand, const u32* __restrict__ keys,
            const int* __restrict__ imidx, u64* __restrict__ sorted)
{
  __shared__ u64 sm[1024];
  int t = threadIdx.x, g = blockIdx.x;
#pragma unroll
  for (int p = 0; p < 2; ++p) {
    int s = t + p * 512;
    u64 e = ~0ull;
    if (s < KTOP) {
      u32 i = cand[g * 1024 + s];
      u32 k = mkey(keys, imidx, (int)i, g);
      e = ((u64)(~k) << 32) | (u64)i;
    }
    sm[s] = e;
  }
  __syncthreads();
  for (int kk = 2; kk <= 1024; kk <<= 1)
    for (int j = kk >> 1; j > 0; j >>= 1) {
#pragma unroll
      for (int p = 0; p < 2; ++p) {
        int i = t + p * 512;
        int ixj = i ^ j;
        if (ixj > i) {
          u64 a = sm[i], b = sm[ixj];
          bool up = ((i & kk) == 0);
          if ((a > b) == up) { sm[i] = b; sm[ixj] = a; }
        }
      }
      __syncthreads();
    }
  sorted[g * 1024 + t] = sm[t];
  sorted[g * 1024 + t + 512] = sm[t + 512];
}

// ---------------- fused gather: sorted -> (idx, sc, box, inval) + offset boxes
__global__ void gather_k(const u64* __restrict__ sorted, const float* __restrict__ boxes,
                         u32* __restrict__ idx_k, float* __restrict__ sc_k,
                         float4* __restrict__ box_k, u64* __restrict__ inval,
                         float4* __restrict__ ob, float* __restrict__ area)
{
  __shared__ u32 smax;
  int t = threadIdx.x, g = blockIdx.x;
  if (t == 0) smax = 0;
  __syncthreads();
  u64 e = sorted[g * 1024 + t];
  u32 idx = (u32)e;
  u32 k = ~(u32)(e >> 32);
  float sc = fkeyinv(k);
  bool val = (t < KTOP) && (sc > 0.f);
  float4 b = make_float4(0.f, 0.f, 0.f, 0.f);
  if (t < KTOP) {
    idx_k[g * 1024 + t] = idx;
    sc_k[g * 1024 + t] = sc;
    b = ((const float4*)boxes)[idx];
    box_k[g * 1024 + t] = b;
    u32 m1 = __float_as_uint(b.x) > __float_as_uint(b.y) ? __float_as_uint(b.x) : __float_as_uint(b.y);
    u32 m2 = __float_as_uint(b.z) > __float_as_uint(b.w) ? __float_as_uint(b.z) : __float_as_uint(b.w);
    atomicMax(&smax, m1 > m2 ? m1 : m2);   // boxes clipped >=0 -> uint cmp exact
  }
  u64 bal = __ballot(!val);
  if ((t & 63) == 0) inval[g * 16 + (t >> 6)] = bal;
  __syncthreads();
  float mx = __uint_as_float(smax);
  if (t < KTOP) {
    float off = (float)(idx % NCLS) * (mx + 1.0f);
    float4 o = make_float4(b.x + off, b.y + off, b.z + off, b.w + off);
    ob[g * 1024 + t] = o;
    area[g * 1024 + t] = (o.z - o.x) * (o.w - o.y);
  }
}

// ---------------- NMS suppression bit-matrix
__global__ __launch_bounds__(256)
void nmsmat_k(const float4* __restrict__ ob, const float* __restrict__ area, u64* __restrict__ Mrow)
{
  __shared__ float4 sob[KTOP];
  __shared__ float sar[KTOP];
  int t = threadIdx.x, g = blockIdx.y;
  for (int s = t; s < KTOP; s += 256) { sob[s] = ob[g * 1024 + s]; sar[s] = area[g * 1024 + s]; }
  __syncthreads();
  int w = blockIdx.x * 256 + t;
  if (w >= KTOP * 16) return;
  int i = w >> 4, jw = w & 15;
  float4 bi = sob[i];
  float ai = sar[i];
  u64 bits = 0;
  int jbase = jw * 64;
  for (int b = 0; b < 64; ++b) {
    int j = jbase + b;
    if (j < KTOP && j > i) {
      float4 bj = sob[j];
      float iw = fminf(bi.z, bj.z) - fmaxf(bi.x, bj.x); iw = fmaxf(iw, 0.f);
      float ih = fminf(bi.w, bj.w) - fmaxf(bi.y, bj.y); ih = fmaxf(ih, 0.f);
      float inter = iw * ih;
      float iou = inter / (ai + sar[j] - inter + 1e-9f);
      if (iou > 0.5f) bits |= (1ull << b);
    }
  }
  Mrow[(size_t)(g * KTOP + i) * 16 + jw] = bits;
}

// ---------------- sequential greedy scan (single wave per image)
__global__ void nmsscan_k(const u64* __restrict__ Mrow, const u64* __restrict__ inval,
                          const u32* __restrict__ idx_k, const float* __restrict__ sc_k,
                          const float4* __restrict__ box_k, float* __restrict__ out)
{
  int lane = threadIdx.x;
  int g = blockIdx.x;
  u64 remv = (lane < 16) ? inval[g * 16 + lane] : 0ull;
  __shared__ int keepL[IMTOP];
  int nk = 0;
  for (int i = 0; i < KTOP; ++i) {
    int wd = i >> 6;
    u64 rw = __shfl(remv, wd);
    if (!((rw >> (i & 63)) & 1ull)) {
      if (lane < 16) remv |= Mrow[(size_t)(g * KTOP + i) * 16 + lane];
      if (lane == 0) keepL[nk] = i;
      ++nk;
      if (nk == IMTOP) break;
    }
  }
  __syncthreads();
  for (int s = lane; s < IMTOP; s += 64) {
    float4 b = make_float4(0.f, 0.f, 0.f, 0.f);
    float sc = 0.f, cf = -1.f;
    if (s < nk) {
      int i = keepL[s];
      b = box_k[g * 1024 + i];
      sc = sc_k[g * 1024 + i];
      cf = (float)(idx_k[g * 1024 + i] % NCLS);
    }
    ((float4*)out)[g * IMTOP + s] = b;
    out[800 + g * IMTOP + s] = sc;
    out[1000 + g * IMTOP + s] = cf;
  }
}

extern "C" void kernel_launch(void* const* d_in, const int* in_sizes, int n_in,
                              void* d_out, int out_size, void* d_ws, size_t ws_size,
                              hipStream_t stream) {
  (void)in_sizes; (void)n_in; (void)out_size;
  const float* roi  = (const float*)d_in[0];
  const float* prop = (const float*)d_in[1];
  const int*   imix = (const int*)d_in[2];
  const float* imsz = (const float*)d_in[3];
  const float* fc1w = (const float*)d_in[4];
  const float* fc1b = (const float*)d_in[5];
  const float* fc2w = (const float*)d_in[6];
  const float* fc2b = (const float*)d_in[7];
  const float* clsw = (const float*)d_in[8];
  const float* clsb = (const float*)d_in[9];
  const float* regw = (const float*)d_in[10];
  const float* regb = (const float*)d_in[11];
  float* out = (float*)d_out;

  char* ws = (char*)d_ws;
  size_t o = 0;
  auto alloc = [&](size_t bytes) { size_t r = o; o += (bytes + 255) & ~(size_t)255; return r; };
  float* C1    = (float*)(ws + alloc((size_t)R_ROIS * HID * 4));
  float* C2    = (float*)(ws + alloc((size_t)R_ROIS * HID * 4));   // contiguous with C1
  float* HEADS = (float*)(ws + alloc((size_t)R_ROIS * NHEAD * 4));
  u32*   KEYS  = (u32*)  (ws + alloc((size_t)RC * 4));
  float* BOXES = (float*)(ws + alloc((size_t)RC * 16));
  u64*   MROW  = (u64*)  (ws + alloc((size_t)2 * KTOP * 16 * 8));
  u64*   SORTED= (u64*)  (ws + alloc(2 * 1024 * 8));
  u32*   CAND  = (u32*)  (ws + alloc(2 * 1024 * 4));
  u32*   IDXK  = (u32*)  (ws + alloc(2 * 1024 * 4));
  float* SCK   = (float*)(ws + alloc(2 * 1024 * 4));
  float4* BOXK = (float4*)(ws + alloc(2 * 1024 * 16));
  float4* OBK  = (float4*)(ws + alloc(2 * 1024 * 16));
  float* AREA  = (float*)(ws + alloc(2 * 1024 * 4));
  u64*   INVAL = (u64*)  (ws + alloc(2 * 16 * 8));
  size_t zz0 = o;
  u32* HIST1 = (u32*)(ws + alloc(2 * 2048 * 4));
  u32* HIST2 = (u32*)(ws + alloc(2 * 2048 * 4));
  u32* HIST3 = (u32*)(ws + alloc(2 * 1024 * 4));
  u32* SEL   = (u32*)(ws + alloc(2 * 8 * 4));
  u32* CNTGT = (u32*)(ws + alloc(2 * 4));
  size_t zzBytes = o - zz0;
  u32* EQCNT = (u32*)(ws + alloc(2 * 160 * 4));
  u32* EQOFF = (u32*)(ws + alloc(2 * 160 * 4));

  // fp16-split extras
  f16* A1h = (f16*)(ws + alloc((size_t)R_ROIS * CIN * 2));
  f16* A2h = (f16*)(ws + alloc((size_t)R_ROIS * CIN * 2));
  f16* B1h = (f16*)(ws + alloc((size_t)HID * CIN * 2));
  f16* B2h = (f16*)(ws + alloc((size_t)HID * CIN * 2));
  f16* X1h = (f16*)(ws + alloc((size_t)R_ROIS * HID * 2));
  f16* X2h = (f16*)(ws + alloc((size_t)R_ROIS * HID * 2));
  f16* W1h = (f16*)(ws + alloc((size_t)HID * HID * 2));
  f16* W2h = (f16*)(ws + alloc((size_t)HID * HID * 2));
  f16* Y1h = (f16*)(ws + alloc((size_t)R_ROIS * HID * 2));
  f16* Y2h = (f16*)(ws + alloc((size_t)R_ROIS * HID * 2));
  f16* WH1 = (f16*)(ws + alloc((size_t)512 * HID * 2));
  f16* WH2 = (f16*)(ws + alloc((size_t)512 * HID * 2));
  bool fp16ok = (o <= ws_size);

  hipMemsetAsync(C1, 0, (size_t)2 * R_ROIS * HID * 4, stream);   // C1+C2 contiguous
  hipMemsetAsync(ws + zz0, 0, zzBytes, stream);

  if (fp16ok) {
    // fused splits: roi, fc1_w, fc2_w  (counts in float4)
    split3_k<<<2048, 256, 0, stream>>>(roi, R_ROIS * CIN / 4, fc1w, HID * CIN / 4,
                                       fc2w, HID * HID / 4,
                                       A1h, A2h, B1h, B2h, W1h, W2h);
    packhead_k<<<512, 256, 0, stream>>>(clsw, regw, WH1, WH2);
    biasfill_k<<<(R_ROIS * NHEAD + 255) / 256, 256, 0, stream>>>(clsb, regb, HEADS);
    // FC1 (splitK=4, kLen=3136) — 512-thread blocks, 16 waves/CU
    gemm_f16x3<<<dim3(8, 16, 4), 512, 0, stream>>>(A1h, A2h, B1h, B2h, C1, R_ROIS, HID, CIN, 3136);
    bias_relu_split_k<<<(R_ROIS * HID + 255) / 256, 256, 0, stream>>>(C1, fc1b, X1h, X2h, R_ROIS * HID);
    // FC2 (splitK=4, kLen=256)
    gemm_f16x3<<<dim3(8, 16, 4), 512, 0, stream>>>(X1h, X2h, W1h, W2h, C2, R_ROIS, HID, HID, 256);
    bias_relu_split_k<<<(R_ROIS * HID + 255) / 256, 256, 0, stream>>>(C2, fc2b, Y1h, Y2h, R_ROIS * HID);
    // heads (N=401, col-guarded; HEADS prefilled with bias; splitK=8 for grid fill)
    gemm_f16x3<<<dim3(4, 16, 8), 512, 0, stream>>>(Y1h, Y2h, WH1, WH2, HEADS, R_ROIS, NHEAD, HID, 128);
  } else {
    gemm128<<<dim3(8, 16, 4), 256, 0, stream>>>(roi, CIN, fc1w, CIN, C1, R_ROIS, HID, 3136);
    bias_relu_k<<<2000, 256, 0, stream>>>(C1, fc1b, R_ROIS * HID / 4);
    gemm128<<<dim3(8, 16, 4), 256, 0, stream>>>(C1, HID, fc2w, HID, C2, R_ROIS, HID, 256);
    bias_relu_k<<<2000, 256, 0, stream>>>(C2, fc2b, R_ROIS * HID / 4);
    gemm_heads<<<dim3(7, 32), 256, 0, stream>>>(C2, clsw, clsb, regw, regb, HEADS);
  }
  // softmax + decode + mask
  decode_k<<<500, 256, 0, stream>>>(HEADS, prop, imix, imsz, KEYS, BOXES);
  // exact top-1000 threshold per image
  hist_k<<<dim3(128, 2), 256, 0, stream>>>(KEYS, imix, SEL, HIST1, 1, 2048);
  find_k<<<2, 256, 0, stream>>>(HIST1, 2048, SEL, 1);
  hist_k<<<dim3(128, 2), 256, 0, stream>>>(KEYS, imix, SEL, HIST2, 2, 2048);
  find_k<<<2, 256, 0, stream>>>(HIST2, 2048, SEL, 2);
  hist_k<<<dim3(128, 2), 256, 0, stream>>>(KEYS, imix, SEL, HIST3, 3, 1024);
  find_k<<<2, 256, 0, stream>>>(HIST3, 1024, SEL, 3);
  // stable tie compaction + sort
  eqcount_k<<<dim3(NCHUNK, 2), 1024, 0, stream>>>(KEYS, imix, SEL, EQCNT);
  eqscan_k<<<2, 256, 0, stream>>>(EQCNT, EQOFF);
  emit_k<<<dim3(NCHUNK, 2), 1024, 0, stream>>>(KEYS, imix, SEL, EQOFF, CNTGT, CAND);
  sort_k<<<2, 512, 0, stream>>>(CAND, KEYS, imix, SORTED);
  // gather (fused) + NMS
  gather_k<<<2, 1024, 0, stream>>>(SORTED, BOXES, IDXK, SCK, BOXK, INVAL, OBK, AREA);
  nmsmat_k<<<dim3(63, 2), 256, 0, stream>>>(OBK, AREA, MROW);
  nmsscan_k<<<2, 64, 0, stream>>>(MROW, INVAL, IDXK, SCK, BOXK, out);
}

// Round 9
// 634.008 us; speedup vs baseline: 1.0701x; 1.0701x over previous
//
#include <hip/hip_runtime.h>
#include <cstdint>

typedef unsigned int u32;
typedef unsigned long long u64;
typedef _Float16 f16;
typedef f16 f16x8 __attribute__((ext_vector_type(8)));
typedef f16 f16x4 __attribute__((ext_vector_type(4)));
typedef float f32x4 __attribute__((ext_vector_type(4)));

#define R_ROIS 2000
#define CIN 12544
#define HID 1024
#define NCLS 80
#define NHEAD 401
#define RC (R_ROIS*NCLS)       // 160000
#define KTOP 1000
#define IMTOP 100
#define KEY_NEG1 0x407FFFFFu   // fkey(-1.0f)
#define BBOX_CLIPV 4.135166556742356f
#define NCHUNK 157             // ceil(160000/1024)

__device__ __forceinline__ u32 fkey(float f) {
  u32 u = __float_as_uint(f);
  return (u & 0x80000000u) ? ~u : (u | 0x80000000u);
}
__device__ __forceinline__ float fkeyinv(u32 k) {
  u32 b = (k & 0x80000000u) ? (k & 0x7FFFFFFFu) : ~k;
  return __uint_as_float(b);
}
__device__ __forceinline__ u32 mkey(const u32* keys, const int* imidx, int i, int g) {
  int r = i / NCLS;
  return (imidx[r] == g) ? keys[i] : KEY_NEG1;
}

__device__ __forceinline__ void lds16(const f16* gsrc, f16* ldst) {
  __builtin_amdgcn_global_load_lds(
      (const __attribute__((address_space(1))) void*)gsrc,
      (__attribute__((address_space(3))) void*)ldst, 16, 0, 0);
}

// ================= fp16-split MFMA GEMM, 2-phase prefetch, 8 waves =================
// C[M,N] += sum_k (A1+A2)[m,k]*(B1+B2)[n,k] ~= A1B1 + A1B2 + A2B1.
// NT layout, K pitch = K. 128x128 tile, BK=32, 8 waves (2x4 of 64x32), 512 thr.
// XCD-aware bijective block remap (round-8 PMC: 500 MB L2-fill vs 150 MB ideal,
// because blocks sharing an A-panel round-robin across the 8 per-XCD L2s):
// nlid = (lid&7)*cpx + lid>>3 groups {all n-cols x 8 m-rows x 1 k-slice} per
// XCD -> per-XCD fill ~26 MB. Pure bijection: wrong XCD heuristic only costs
// speed, never correctness.
// LDS swizzle (verified r7: conflicts 12.8M->0) + 2-phase global_load_lds
// prefetch with raw s_barrier + vmcnt(0).
__global__ __launch_bounds__(512, 4)
void gemm_f16x3(const f16* __restrict__ A1, const f16* __restrict__ A2,
                const f16* __restrict__ B1, const f16* __restrict__ B2,
                float* __restrict__ C, int M, int N, int K, int kLen)
{
  __shared__ __align__(16) f16 As1[2][128 * 32];
  __shared__ __align__(16) f16 As2[2][128 * 32];
  __shared__ __align__(16) f16 Bs1[2][128 * 32];
  __shared__ __align__(16) f16 Bs2[2][128 * 32];

  // ---- XCD-aware remap (requires nblk % 8 == 0; all launches satisfy) ----
  int gx = gridDim.x, gy = gridDim.y;
  int nblk = gx * gy * gridDim.z;
  int lid = blockIdx.x + gx * (blockIdx.y + gy * blockIdx.z);
  int cpx = nblk >> 3;
  int nlid = (lid & 7) * cpx + (lid >> 3);
  int bx = nlid % gx;
  int rem = nlid / gx;
  int by = rem % gy;
  int bz = rem / gy;

  int t = threadIdx.x;
  int w = t >> 6, lane = t & 63;
  int wm = w >> 2, wn = w & 3;        // 2 x 4 wave grid; wave tile 64(M) x 32(N)
  int m0 = by * 128, n0 = bx * 128;
  int k0 = bz * kLen;

  f32x4 acc[4][2];
#pragma unroll
  for (int mi = 0; mi < 4; ++mi)
#pragma unroll
    for (int ni = 0; ni < 2; ++ni)
#pragma unroll
      for (int r = 0; r < 4; ++r) acc[mi][ni][r] = 0.f;

  // staging: 512 segs of 16B per tile; thread t covers seg t (1 per array).
  // global source col-seg XOR-swizzled so linear LDS slot (row,j) holds
  // data seg (row, j ^ ((row>>1)&3)).
  int row0 = t >> 2;       int j0 = (t & 3) ^ ((row0 >> 1) & 3);
  int rmA0 = m0 + row0; if (rmA0 > M - 1) rmA0 = M - 1;
  int rnB0 = n0 + row0; if (rnB0 > N - 1) rnB0 = N - 1;
  size_t a0 = (size_t)rmA0 * K + j0 * 8;
  size_t b0 = (size_t)rnB0 * K + j0 * 8;
  int sw0 = (w * 64) * 8;          // wave-uniform LDS base (elements)

  int rrow = lane & 15;
  int cxor = (rrow >> 1) & 3;                  // (row>>1)&3 within tile
  int rsel = ((lane >> 4) ^ cxor) * 8;         // swizzled 16B-seg on read

  int nt = kLen / 32;
  // prologue: stage tile 0 into buf 0
  {
    int kb = k0;
    lds16(A1 + a0 + kb, &As1[0][sw0]);
    lds16(A2 + a0 + kb, &As2[0][sw0]);
    lds16(B1 + b0 + kb, &Bs1[0][sw0]);
    lds16(B2 + b0 + kb, &Bs2[0][sw0]);
  }
  asm volatile("s_waitcnt vmcnt(0)" ::: "memory");
  __builtin_amdgcn_s_barrier();
  __builtin_amdgcn_sched_barrier(0);

  int cur = 0;
  for (int tt = 0; tt < nt; ++tt) {
    if (tt + 1 < nt) {                 // issue next-tile loads first (overlap)
      int kb = k0 + (tt + 1) * 32;
      int nx = cur ^ 1;
      lds16(A1 + a0 + kb, &As1[nx][sw0]);
      lds16(A2 + a0 + kb, &As2[nx][sw0]);
      lds16(B1 + b0 + kb, &Bs1[nx][sw0]);
      lds16(B2 + b0 + kb, &Bs2[nx][sw0]);
    }
    __builtin_amdgcn_sched_barrier(0);

    f16x8 af1[4], af2[4], bf1[2], bf2[2];
#pragma unroll
    for (int mi = 0; mi < 4; ++mi) {
      int ra = (wm * 64 + mi * 16 + rrow) * 32 + rsel;
      af1[mi] = *(const f16x8*)&As1[cur][ra];
      af2[mi] = *(const f16x8*)&As2[cur][ra];
    }
#pragma unroll
    for (int ni = 0; ni < 2; ++ni) {
      int rb = (wn * 32 + ni * 16 + rrow) * 32 + rsel;
      bf1[ni] = *(const f16x8*)&Bs1[cur][rb];
      bf2[ni] = *(const f16x8*)&Bs2[cur][rb];
    }
    __builtin_amdgcn_s_setprio(1);
#pragma unroll
    for (int mi = 0; mi < 4; ++mi)
#pragma unroll
      for (int ni = 0; ni < 2; ++ni) {
        acc[mi][ni] = __builtin_amdgcn_mfma_f32_16x16x32_f16(af1[mi], bf1[ni], acc[mi][ni], 0, 0, 0);
        acc[mi][ni] = __builtin_amdgcn_mfma_f32_16x16x32_f16(af1[mi], bf2[ni], acc[mi][ni], 0, 0, 0);
        acc[mi][ni] = __builtin_amdgcn_mfma_f32_16x16x32_f16(af2[mi], bf1[ni], acc[mi][ni], 0, 0, 0);
      }
    __builtin_amdgcn_s_setprio(0);
    __builtin_amdgcn_sched_barrier(0);
    asm volatile("s_waitcnt vmcnt(0)" ::: "memory");   // next-tile stage landed
    __builtin_amdgcn_s_barrier();
    __builtin_amdgcn_sched_barrier(0);
    cur ^= 1;
  }

  // epilogue: C/D layout col=lane&15, row=(lane>>4)*4+r (m89-verified)
  int crow = m0 + wm * 64 + (lane >> 4) * 4;
  int ccol = n0 + wn * 32 + (lane & 15);
#pragma unroll
  for (int mi = 0; mi < 4; ++mi)
#pragma unroll
    for (int r = 0; r < 4; ++r) {
      int rm = crow + mi * 16 + r;
      if (rm < M) {
#pragma unroll
        for (int ni = 0; ni < 2; ++ni) {
          int cc = ccol + ni * 16;
          if (cc < N) atomicAdd(&C[(size_t)rm * N + cc], acc[mi][ni][r]);
        }
      }
    }
}

// fused split of roi / fc1_w / fc2_w into fp16 (hi, lo) pairs; counts in float4
__global__ void split3_k(const float* __restrict__ s0, int c0,
                         const float* __restrict__ s1, int c1,
                         const float* __restrict__ s2, int c2,
                         f16* __restrict__ d0a, f16* __restrict__ d0b,
                         f16* __restrict__ d1a, f16* __restrict__ d1b,
                         f16* __restrict__ d2a, f16* __restrict__ d2b)
{
  int total = c0 + c1 + c2;
  for (int i = blockIdx.x * blockDim.x + threadIdx.x; i < total; i += gridDim.x * blockDim.x) {
    const float* src; f16 *da, *db; int j;
    if (i < c0) { src = s0; da = d0a; db = d0b; j = i; }
    else if (i < c0 + c1) { src = s1; da = d1a; db = d1b; j = i - c0; }
    else { src = s2; da = d2a; db = d2b; j = i - c0 - c1; }
    float4 v = ((const float4*)src)[j];
    f16x4 o1, o2;
    o1[0] = (f16)v.x; o2[0] = (f16)(v.x - (float)o1[0]);
    o1[1] = (f16)v.y; o2[1] = (f16)(v.y - (float)o1[1]);
    o1[2] = (f16)v.z; o2[2] = (f16)(v.z - (float)o1[2]);
    o1[3] = (f16)v.w; o2[3] = (f16)(v.w - (float)o1[3]);
    ((f16x4*)da)[j] = o1;
    ((f16x4*)db)[j] = o2;
  }
}

// pack [cls_w;reg_w] into 512-row fp16 split (rows >=401 clamp to 400)
__global__ void packhead_k(const float* __restrict__ clsw, const float* __restrict__ regw,
                           f16* __restrict__ W1, f16* __restrict__ W2)
{
  int i = blockIdx.x * blockDim.x + threadIdx.x;   // float4 index over 512*256
  if (i >= 512 * 256) return;
  int r = i >> 8, c4 = i & 255;
  int rr = (r < NHEAD) ? r : (NHEAD - 1);
  const float* src = (rr < 81) ? (clsw + (size_t)rr * HID) : (regw + (size_t)(rr - 81) * HID);
  float4 v = ((const float4*)src)[c4];
  f16x4 o1, o2;
  o1[0] = (f16)v.x; o2[0] = (f16)(v.x - (float)o1[0]);
  o1[1] = (f16)v.y; o2[1] = (f16)(v.y - (float)o1[1]);
  o1[2] = (f16)v.z; o2[2] = (f16)(v.z - (float)o1[2]);
  o1[3] = (f16)v.w; o2[3] = (f16)(v.w - (float)o1[3]);
  ((f16x4*)W1)[i] = o1;
  ((f16x4*)W2)[i] = o2;
}

// prefill HEADS with bias (heads gemm atomicAdds on top)
__global__ void biasfill_k(const float* __restrict__ clsb, const float* __restrict__ regb,
                           float* __restrict__ H)
{
  int i = blockIdx.x * blockDim.x + threadIdx.x;
  if (i >= R_ROIS * NHEAD) return;
  int c = i % NHEAD;
  H[i] = (c < 81) ? clsb[c] : regb[c - 81];
}

// bias+relu on f32 activations, emit fp16 split
__global__ void bias_relu_split_k(const float* __restrict__ X, const float* __restrict__ bias,
                                  f16* __restrict__ H1, f16* __restrict__ H2, int total)
{
  int i = blockIdx.x * blockDim.x + threadIdx.x;
  if (i >= total) return;
  float v = fmaxf(X[i] + bias[i & (HID - 1)], 0.f);
  f16 a = (f16)v;
  H1[i] = a;
  H2[i] = (f16)(v - (float)a);
}

// ---------------- f32 GEMM (fallback path) ----------------
__global__ __launch_bounds__(256, 2)
void gemm128(const float* __restrict__ A, int lda,
             const float* __restrict__ B, int ldb,
             float* __restrict__ C, int M, int N, int kLen)
{
  __shared__ float As[128][20];
  __shared__ float Bs[128][20];
  int t = threadIdx.x;
  int tx = t & 15, ty = t >> 4;
  int m0 = blockIdx.y * 128, n0 = blockIdx.x * 128;
  int k0 = blockIdx.z * kLen;
  float acc[8][8];
#pragma unroll
  for (int i = 0; i < 8; ++i)
#pragma unroll
    for (int j = 0; j < 8; ++j) acc[i][j] = 0.f;

  int lr = t >> 2;
  int lk = (t & 3) * 4;

  for (int ks = 0; ks < kLen; ks += 16) {
#pragma unroll
    for (int p = 0; p < 2; ++p) {
      int row = lr + p * 64;
      int rm = m0 + row; if (rm > M - 1) rm = M - 1;
      float4 av = *(const float4*)(A + (size_t)rm * lda + k0 + ks + lk);
      *(float4*)&As[row][lk] = av;
      int rn = n0 + row; if (rn > N - 1) rn = N - 1;
      float4 bv = *(const float4*)(B + (size_t)rn * ldb + k0 + ks + lk);
      *(float4*)&Bs[row][lk] = bv;
    }
    __syncthreads();
#pragma unroll
    for (int kk = 0; kk < 16; kk += 4) {
      float4 a4[8], b4[8];
#pragma unroll
      for (int i = 0; i < 8; ++i) a4[i] = *(const float4*)&As[ty + (i << 4)][kk];
#pragma unroll
      for (int j = 0; j < 8; ++j) b4[j] = *(const float4*)&Bs[tx + (j << 4)][kk];
#pragma unroll
      for (int i = 0; i < 8; ++i)
#pragma unroll
        for (int j = 0; j < 8; ++j) {
          acc[i][j] += a4[i].x * b4[j].x;
          acc[i][j] += a4[i].y * b4[j].y;
          acc[i][j] += a4[i].z * b4[j].z;
          acc[i][j] += a4[i].w * b4[j].w;
        }
    }
    __syncthreads();
  }
#pragma unroll
  for (int i = 0; i < 8; ++i) {
    int rm = m0 + ty + (i << 4);
    if (rm < M) {
#pragma unroll
      for (int j = 0; j < 8; ++j) {
        int rn = n0 + tx + (j << 4);
        atomicAdd(&C[(size_t)rm * N + rn], acc[i][j]);
      }
    }
  }
}

__global__ void bias_relu_k(float* __restrict__ X, const float* __restrict__ bias, int total4)
{
  int i4 = blockIdx.x * blockDim.x + threadIdx.x;
  if (i4 >= total4) return;
  int c4 = i4 & 255;
  float4 v = ((float4*)X)[i4];
  float4 b = ((const float4*)bias)[c4];
  v.x = fmaxf(v.x + b.x, 0.f);
  v.y = fmaxf(v.y + b.y, 0.f);
  v.z = fmaxf(v.z + b.z, 0.f);
  v.w = fmaxf(v.w + b.w, 0.f);
  ((float4*)X)[i4] = v;
}

// ---------------- heads (fallback f32): H[2000][401] = A @ [cls_w;reg_w]^T + bias
__global__ __launch_bounds__(256)
void gemm_heads(const float* __restrict__ A,
                const float* __restrict__ clsw, const float* __restrict__ clsb,
                const float* __restrict__ regw, const float* __restrict__ regb,
                float* __restrict__ H)
{
  __shared__ float As[64][36];
  __shared__ float Bs[64][36];
  int t = threadIdx.x;
  int tx = t & 15, ty = t >> 4;
  int m0 = blockIdx.y * 64, n0 = blockIdx.x * 64;
  float acc[4][4] = {};
  int lr = t >> 3;
  int lk = (t & 7) * 4;

  for (int ks = 0; ks < HID; ks += 32) {
#pragma unroll
    for (int p = 0; p < 2; ++p) {
      int row = lr + p * 32;
      int rm = m0 + row; if (rm > R_ROIS - 1) rm = R_ROIS - 1;
      *(float4*)&As[row][lk] = *(const float4*)(A + (size_t)rm * HID + ks + lk);
      int rn = n0 + row; if (rn > NHEAD - 1) rn = NHEAD - 1;
      const float* bp = (rn < 81) ? (clsw + (size_t)rn * HID) : (regw + (size_t)(rn - 81) * HID);
      *(float4*)&Bs[row][lk] = *(const float4*)(bp + ks + lk);
    }
    __syncthreads();
#pragma unroll
    for (int kk = 0; kk < 32; kk += 4) {
      float4 a4[4], b4[4];
#pragma unroll
      for (int i = 0; i < 4; ++i) a4[i] = *(const float4*)&As[ty + (i << 4)][kk];
#pragma unroll
      for (int j = 0; j < 4; ++j) b4[j] = *(const float4*)&Bs[tx + (j << 4)][kk];
#pragma unroll
      for (int i = 0; i < 4; ++i)
#pragma unroll
        for (int j = 0; j < 4; ++j) {
          acc[i][j] += a4[i].x * b4[j].x;
          acc[i][j] += a4[i].y * b4[j].y;
          acc[i][j] += a4[i].z * b4[j].z;
          acc[i][j] += a4[i].w * b4[j].w;
        }
    }
    __syncthreads();
  }
#pragma unroll
  for (int i = 0; i < 4; ++i) {
    int rm = m0 + ty + (i << 4);
#pragma unroll
    for (int j = 0; j < 4; ++j) {
      int rn = n0 + tx + (j << 4);
      if (rm < R_ROIS && rn < NHEAD) {
        float b = (rn < 81) ? clsb[rn] : regb[rn - 81];
        H[(size_t)rm * NHEAD + rn] = acc[i][j] + b;
      }
    }
  }
}

// ---------------- softmax + box decode + mask; one wave per roi
__global__ __launch_bounds__(256)
void decode_k(const float* __restrict__ H, const float* __restrict__ prop,
              const int* __restrict__ imidx, const float* __restrict__ imsz,
              u32* __restrict__ keys, float* __restrict__ boxes)
{
  int lane = threadIdx.x & 63;
  int r = blockIdx.x * 4 + (threadIdx.x >> 6);
  const float* h = H + (size_t)r * NHEAD;
  float l0 = h[lane];
  float l1 = (lane < 17) ? h[64 + lane] : -1e30f;
  float mx = fmaxf(l0, l1);
#pragma unroll
  for (int o = 32; o; o >>= 1) mx = fmaxf(mx, __shfl_xor(mx, o));
  float e0 = expf(l0 - mx);
  float e1 = (lane < 17) ? expf(l1 - mx) : 0.f;
  float s = e0 + e1;
#pragma unroll
  for (int o = 32; o; o >>= 1) s += __shfl_xor(s, o);

  float px1 = prop[r * 4 + 0], py1 = prop[r * 4 + 1];
  float px2 = prop[r * 4 + 2], py2 = prop[r * 4 + 3];
  float pw = px2 - px1, ph = py2 - py1;
  float pcx = px1 + 0.5f * pw, pcy = py1 + 0.5f * ph;
  int g = imidx[r];
  float imh = imsz[g * 2 + 0], imw = imsz[g * 2 + 1];

#pragma unroll
  for (int q = 0; q < 2; ++q) {
    int c = (q == 0) ? lane : 64 + lane;
    bool on = (q == 0) ? true : (lane < 16);
    if (on) {
      float e = (q == 0) ? e0 : e1;
      float scr = e / s;
      const float* rg = h + 81 + c * 4;
      float dx = rg[0] * 0.1f, dy = rg[1] * 0.1f;
      float dw = fminf(rg[2] * 0.2f, BBOX_CLIPV);
      float dh = fminf(rg[3] * 0.2f, BBOX_CLIPV);
      float cx = dx * pw + pcx, cy = dy * ph + pcy;
      float w = expf(dw) * pw, hh = expf(dh) * ph;
      float x1 = cx - 0.5f * w, y1 = cy - 0.5f * hh;
      float x2 = cx + 0.5f * w, y2 = cy + 0.5f * hh;
      x1 = fminf(fmaxf(x1, 0.f), imw);
      x2 = fminf(fmaxf(x2, 0.f), imw);
      y1 = fminf(fmaxf(y1, 0.f), imh);
      y2 = fminf(fmaxf(y2, 0.f), imh);
      float bw = x2 - x1, bh = y2 - y1;
      bool msk = (scr > 0.05f) && (bw >= 1.f) && (bh >= 1.f);
      float sm = msk ? scr : -1.f;
      int idx = r * 80 + c;
      keys[idx] = fkey(sm);
      ((float4*)boxes)[idx] = make_float4(x1, y1, x2, y2);
    }
  }
}

// ---------------- exact rank-1000 threshold: 3-level radix histogram refine
__global__ void hist_k(const u32* __restrict__ keys, const int* __restrict__ imidx,
                       const u32* __restrict__ sel, u32* __restrict__ hist, int level, int nbins)
{
  __shared__ u32 lh[2048];
  int t = threadIdx.x, g = blockIdx.y;
  for (int b = t; b < 2048; b += 256) lh[b] = 0;
  __syncthreads();
  u32 b1 = 0, pre21 = 0;
  if (level == 2) b1 = sel[g * 8 + 0];
  if (level == 3) pre21 = (sel[g * 8 + 0] << 11) | sel[g * 8 + 1];
  for (int i = blockIdx.x * 256 + t; i < RC; i += gridDim.x * 256) {
    u32 k = mkey(keys, imidx, i, g);
    if (level == 1) atomicAdd(&lh[k >> 21], 1u);
    else if (level == 2) { if ((k >> 21) == b1) atomicAdd(&lh[(k >> 10) & 0x7FFu], 1u); }
    else { if ((k >> 10) == pre21) atomicAdd(&lh[k & 0x3FFu], 1u); }
  }
  __syncthreads();
  for (int b = t; b < nbins; b += 256) { u32 v = lh[b]; if (v) atomicAdd(&hist[g * nbins + b], v); }
}

__global__ void find_k(const u32* __restrict__ hist, int nbins, u32* __restrict__ sel, int level)
{
  __shared__ u32 sh[256];
  int t = threadIdx.x, g = blockIdx.x;
  int per = nbins >> 8;
  const u32* h = hist + g * nbins;
  u32 mySum = 0;
  for (int jj = 0; jj < per; ++jj) mySum += h[t * per + jj];
  u32 base = (level == 1) ? 0u : sel[g * 8 + 3];
  sh[t] = mySum; __syncthreads();
  for (int off = 1; off < 256; off <<= 1) {
    u32 v = (t + off < 256) ? sh[t + off] : 0u; __syncthreads();
    sh[t] += v; __syncthreads();
  }
  u32 c = base + ((t < 255) ? sh[t + 1] : 0u);
  for (int jj = per - 1; jj >= 0; --jj) {
    int b = t * per + jj;
    u32 cnt = h[b];
    if (c < KTOP && c + cnt >= KTOP) {
      if (level == 1) { sel[g * 8 + 0] = (u32)b; sel[g * 8 + 3] = c; }
      else if (level == 2) { sel[g * 8 + 1] = (u32)b; sel[g * 8 + 3] = c; }
      else {
        u32 T = (sel[g * 8 + 0] << 21) | (sel[g * 8 + 1] << 10) | (u32)b;
        sel[g * 8 + 4] = T; sel[g * 8 + 3] = c; sel[g * 8 + 5] = KTOP - c;
      }
    }
    c += cnt;
  }
}

// ---------------- stable selection of ties at T (ascending flat index), then compact
__global__ void eqcount_k(const u32* __restrict__ keys, const int* __restrict__ imidx,
                          const u32* __restrict__ sel, u32* __restrict__ eqcnt)
{
  int g = blockIdx.y, t = threadIdx.x;
  int i = blockIdx.x * 1024 + t;
  u32 T = sel[g * 8 + 4];
  bool eq = (i < RC) && (mkey(keys, imidx, i, g) == T);
  u64 bal = __ballot(eq);
  __shared__ u32 wc[16];
  if ((t & 63) == 0) wc[t >> 6] = (u32)__popcll(bal);
  __syncthreads();
  if (t == 0) {
    u32 sum = 0;
    for (int w = 0; w < 16; ++w) sum += wc[w];
    eqcnt[g * 160 + blockIdx.x] = sum;
  }
}

__global__ void eqscan_k(const u32* __restrict__ eqcnt, u32* __restrict__ eqoff)
{
  __shared__ u32 sh[256];
  int t = threadIdx.x, g = blockIdx.x;
  u32 v = (t < NCHUNK) ? eqcnt[g * 160 + t] : 0u;
  sh[t] = v; __syncthreads();
  for (int off = 1; off < 256; off <<= 1) {
    u32 u = (t >= off) ? sh[t - off] : 0u; __syncthreads();
    sh[t] += u; __syncthreads();
  }
  if (t < NCHUNK) eqoff[g * 160 + t] = sh[t] - v;
}

__global__ void emit_k(const u32* __restrict__ keys, const int* __restrict__ imidx,
                       const u32* __restrict__ sel, const u32* __restrict__ eqoff,
                       u32* __restrict__ cntgt, u32* __restrict__ cand)
{
  int g = blockIdx.y, t = threadIdx.x;
  int i = blockIdx.x * 1024 + t;
  u32 T = sel[g * 8 + 4], m = sel[g * 8 + 5], ra = sel[g * 8 + 3];
  u32 k = (i < RC) ? mkey(keys, imidx, i, g) : 0u;
  if (k > T) { u32 p = atomicAdd(&cntgt[g], 1u); cand[g * 1024 + p] = (u32)i; }
  bool eq = (k == T);
  u64 bal = __ballot(eq);
  int w = t >> 6, lane = t & 63;
  __shared__ u32 wc[16];
  if (lane == 0) wc[w] = (u32)__popcll(bal);
  __syncthreads();
  u32 wb = 0;
  for (int x = 0; x < w; ++x) wb += wc[x];
  if (eq) {
    u32 lanePre = (u32)__popcll(bal & ((1ull << lane) - 1ull));
    u32 rank = eqoff[g * 160 + blockIdx.x] + wb + lanePre;
    if (rank < m) cand[g * 1024 + ra + rank] = (u32)i;
  }
}

// ---------------- bitonic sort of 1000 (pad 1024): key desc, idx asc
__global__ __launch_bounds__(512)
void sort_k(const u32* __restrict__ cand, const u32* __restrict__ keys,
            const int* __restrict__ imidx, u64* __restrict__ sorted)
{
  __shared__ u64 sm[1024];
  int t = threadIdx.x, g = blockIdx.x;
#pragma unroll
  for (int p = 0; p < 2; ++p) {
    int s = t + p * 512;
    u64 e = ~0ull;
    if (s < KTOP) {
      u32 i = cand[g * 1024 + s];
      u32 k = mkey(keys, imidx, (int)i, g);
      e = ((u64)(~k) << 32) | (u64)i;
    }
    sm[s] = e;
  }
  __syncthreads();
  for (int kk = 2; kk <= 1024; kk <<= 1)
    for (int j = kk >> 1; j > 0; j >>= 1) {
#pragma unroll
      for (int p = 0; p < 2; ++p) {
        int i = t + p * 512;
        int ixj = i ^ j;
        if (ixj > i) {
          u64 a = sm[i], b = sm[ixj];
          bool up = ((i & kk) == 0);
          if ((a > b) == up) { sm[i] = b; sm[ixj] = a; }
        }
      }
      __syncthreads();
    }
  sorted[g * 1024 + t] = sm[t];
  sorted[g * 1024 + t + 512] = sm[t + 512];
}

// ---------------- fused gather: sorted -> (idx, sc, box, inval) + offset boxes
__global__ void gather_k(const u64* __restrict__ sorted, const float* __restrict__ boxes,
                         u32* __restrict__ idx_k, float* __restrict__ sc_k,
                         float4* __restrict__ box_k, u64* __restrict__ inval,
                         float4* __restrict__ ob, float* __restrict__ area)
{
  __shared__ u32 smax;
  int t = threadIdx.x, g = blockIdx.x;
  if (t == 0) smax = 0;
  __syncthreads();
  u64 e = sorted[g * 1024 + t];
  u32 idx = (u32)e;
  u32 k = ~(u32)(e >> 32);
  float sc = fkeyinv(k);
  bool val = (t < KTOP) && (sc > 0.f);
  float4 b = make_float4(0.f, 0.f, 0.f, 0.f);
  if (t < KTOP) {
    idx_k[g * 1024 + t] = idx;
    sc_k[g * 1024 + t] = sc;
    b = ((const float4*)boxes)[idx];
    box_k[g * 1024 + t] = b;
    u32 m1 = __float_as_uint(b.x) > __float_as_uint(b.y) ? __float_as_uint(b.x) : __float_as_uint(b.y);
    u32 m2 = __float_as_uint(b.z) > __float_as_uint(b.w) ? __float_as_uint(b.z) : __float_as_uint(b.w);
    atomicMax(&smax, m1 > m2 ? m1 : m2);   // boxes clipped >=0 -> uint cmp exact
  }
  u64 bal = __ballot(!val);
  if ((t & 63) == 0) inval[g * 16 + (t >> 6)] = bal;
  __syncthreads();
  float mx = __uint_as_float(smax);
  if (t < KTOP) {
    float off = (float)(idx % NCLS) * (mx + 1.0f);
    float4 o = make_float4(b.x + off, b.y + off, b.z + off, b.w + off);
    ob[g * 1024 + t] = o;
    area[g * 1024 + t] = (o.z - o.x) * (o.w - o.y);
  }
}

// ---------------- NMS suppression bit-matrix
__global__ __launch_bounds__(256)
void nmsmat_k(const float4* __restrict__ ob, const float* __restrict__ area, u64* __restrict__ Mrow)
{
  __shared__ float4 sob[KTOP];
  __shared__ float sar[KTOP];
  int t = threadIdx.x, g = blockIdx.y;
  for (int s = t; s < KTOP; s += 256) { sob[s] = ob[g * 1024 + s]; sar[s] = area[g * 1024 + s]; }
  __syncthreads();
  int w = blockIdx.x * 256 + t;
  if (w >= KTOP * 16) return;
  int i = w >> 4, jw = w & 15;
  float4 bi = sob[i];
  float ai = sar[i];
  u64 bits = 0;
  int jbase = jw * 64;
  for (int b = 0; b < 64; ++b) {
    int j = jbase + b;
    if (j < KTOP && j > i) {
      float4 bj = sob[j];
      float iw = fminf(bi.z, bj.z) - fmaxf(bi.x, bj.x); iw = fmaxf(iw, 0.f);
      float ih = fminf(bi.w, bj.w) - fmaxf(bi.y, bj.y); ih = fmaxf(ih, 0.f);
      float inter = iw * ih;
      float iou = inter / (ai + sar[j] - inter + 1e-9f);
      if (iou > 0.5f) bits |= (1ull << b);
    }
  }
  Mrow[(size_t)(g * KTOP + i) * 16 + jw] = bits;
}

// ---------------- sequential greedy scan (single wave per image)
__global__ void nmsscan_k(const u64* __restrict__ Mrow, const u64* __restrict__ inval,
                          const u32* __restrict__ idx_k, const float* __restrict__ sc_k,
                          const float4* __restrict__ box_k, float* __restrict__ out)
{
  int lane = threadIdx.x;
  int g = blockIdx.x;
  u64 remv = (lane < 16) ? inval[g * 16 + lane] : 0ull;
  __shared__ int keepL[IMTOP];
  int nk = 0;
  for (int i = 0; i < KTOP; ++i) {
    int wd = i >> 6;
    u64 rw = __shfl(remv, wd);
    if (!((rw >> (i & 63)) & 1ull)) {
      if (lane < 16) remv |= Mrow[(size_t)(g * KTOP + i) * 16 + lane];
      if (lane == 0) keepL[nk] = i;
      ++nk;
      if (nk == IMTOP) break;
    }
  }
  __syncthreads();
  for (int s = lane; s < IMTOP; s += 64) {
    float4 b = make_float4(0.f, 0.f, 0.f, 0.f);
    float sc = 0.f, cf = -1.f;
    if (s < nk) {
      int i = keepL[s];
      b = box_k[g * 1024 + i];
      sc = sc_k[g * 1024 + i];
      cf = (float)(idx_k[g * 1024 + i] % NCLS);
    }
    ((float4*)out)[g * IMTOP + s] = b;
    out[800 + g * IMTOP + s] = sc;
    out[1000 + g * IMTOP + s] = cf;
  }
}

extern "C" void kernel_launch(void* const* d_in, const int* in_sizes, int n_in,
                              void* d_out, int out_size, void* d_ws, size_t ws_size,
                              hipStream_t stream) {
  (void)in_sizes; (void)n_in; (void)out_size;
  const float* roi  = (const float*)d_in[0];
  const float* prop = (const float*)d_in[1];
  const int*   imix = (const int*)d_in[2];
  const float* imsz = (const float*)d_in[3];
  const float* fc1w = (const float*)d_in[4];
  const float* fc1b = (const float*)d_in[5];
  const float* fc2w = (const float*)d_in[6];
  const float* fc2b = (const float*)d_in[7];
  const float* clsw = (const float*)d_in[8];
  const float* clsb = (const float*)d_in[9];
  const float* regw = (const float*)d_in[10];
  const float* regb = (const float*)d_in[11];
  float* out = (float*)d_out;

  char* ws = (char*)d_ws;
  size_t o = 0;
  auto alloc = [&](size_t bytes) { size_t r = o; o += (bytes + 255) & ~(size_t)255; return r; };
  float* C1    = (float*)(ws + alloc((size_t)R_ROIS * HID * 4));
  float* C2    = (float*)(ws + alloc((size_t)R_ROIS * HID * 4));   // contiguous with C1
  float* HEADS = (float*)(ws + alloc((size_t)R_ROIS * NHEAD * 4));
  u32*   KEYS  = (u32*)  (ws + alloc((size_t)RC * 4));
  float* BOXES = (float*)(ws + alloc((size_t)RC * 16));
  u64*   MROW  = (u64*)  (ws + alloc((size_t)2 * KTOP * 16 * 8));
  u64*   SORTED= (u64*)  (ws + alloc(2 * 1024 * 8));
  u32*   CAND  = (u32*)  (ws + alloc(2 * 1024 * 4));
  u32*   IDXK  = (u32*)  (ws + alloc(2 * 1024 * 4));
  float* SCK   = (float*)(ws + alloc(2 * 1024 * 4));
  float4* BOXK = (float4*)(ws + alloc(2 * 1024 * 16));
  float4* OBK  = (float4*)(ws + alloc(2 * 1024 * 16));
  float* AREA  = (float*)(ws + alloc(2 * 1024 * 4));
  u64*   INVAL = (u64*)  (ws + alloc(2 * 16 * 8));
  size_t zz0 = o;
  u32* HIST1 = (u32*)(ws + alloc(2 * 2048 * 4));
  u32* HIST2 = (u32*)(ws + alloc(2 * 2048 * 4));
  u32* HIST3 = (u32*)(ws + alloc(2 * 1024 * 4));
  u32* SEL   = (u32*)(ws + alloc(2 * 8 * 4));
  u32* CNTGT = (u32*)(ws + alloc(2 * 4));
  size_t zzBytes = o - zz0;
  u32* EQCNT = (u32*)(ws + alloc(2 * 160 * 4));
  u32* EQOFF = (u32*)(ws + alloc(2 * 160 * 4));

  // fp16-split extras
  f16* A1h = (f16*)(ws + alloc((size_t)R_ROIS * CIN * 2));
  f16* A2h = (f16*)(ws + alloc((size_t)R_ROIS * CIN * 2));
  f16* B1h = (f16*)(ws + alloc((size_t)HID * CIN * 2));
  f16* B2h = (f16*)(ws + alloc((size_t)HID * CIN * 2));
  f16* X1h = (f16*)(ws + alloc((size_t)R_ROIS * HID * 2));
  f16* X2h = (f16*)(ws + alloc((size_t)R_ROIS * HID * 2));
  f16* W1h = (f16*)(ws + alloc((size_t)HID * HID * 2));
  f16* W2h = (f16*)(ws + alloc((size_t)HID * HID * 2));
  f16* Y1h = (f16*)(ws + alloc((size_t)R_ROIS * HID * 2));
  f16* Y2h = (f16*)(ws + alloc((size_t)R_ROIS * HID * 2));
  f16* WH1 = (f16*)(ws + alloc((size_t)512 * HID * 2));
  f16* WH2 = (f16*)(ws + alloc((size_t)512 * HID * 2));
  bool fp16ok = (o <= ws_size);

  hipMemsetAsync(C1, 0, (size_t)2 * R_ROIS * HID * 4, stream);   // C1+C2 contiguous
  hipMemsetAsync(ws + zz0, 0, zzBytes, stream);

  if (fp16ok) {
    // fused splits: roi, fc1_w, fc2_w  (counts in float4)
    split3_k<<<2048, 256, 0, stream>>>(roi, R_ROIS * CIN / 4, fc1w, HID * CIN / 4,
                                       fc2w, HID * HID / 4,
                                       A1h, A2h, B1h, B2h, W1h, W2h);
    packhead_k<<<512, 256, 0, stream>>>(clsw, regw, WH1, WH2);
    biasfill_k<<<(R_ROIS * NHEAD + 255) / 256, 256, 0, stream>>>(clsb, regb, HEADS);
    // FC1 (splitK=4, kLen=3136) — XCD-aware remap, 16 waves/CU
    gemm_f16x3<<<dim3(8, 16, 4), 512, 0, stream>>>(A1h, A2h, B1h, B2h, C1, R_ROIS, HID, CIN, 3136);
    bias_relu_split_k<<<(R_ROIS * HID + 255) / 256, 256, 0, stream>>>(C1, fc1b, X1h, X2h, R_ROIS * HID);
    // FC2 (splitK=4, kLen=256)
    gemm_f16x3<<<dim3(8, 16, 4), 512, 0, stream>>>(X1h, X2h, W1h, W2h, C2, R_ROIS, HID, HID, 256);
    bias_relu_split_k<<<(R_ROIS * HID + 255) / 256, 256, 0, stream>>>(C2, fc2b, Y1h, Y2h, R_ROIS * HID);
    // heads (N=401, col-guarded; HEADS prefilled with bias; splitK=4)
    gemm_f16x3<<<dim3(4, 16, 4), 512, 0, stream>>>(Y1h, Y2h, WH1, WH2, HEADS, R_ROIS, NHEAD, HID, 256);
  } else {
    gemm128<<<dim3(8, 16, 4), 256, 0, stream>>>(roi, CIN, fc1w, CIN, C1, R_ROIS, HID, 3136);
    bias_relu_k<<<2000, 256, 0, stream>>>(C1, fc1b, R_ROIS * HID / 4);
    gemm128<<<dim3(8, 16, 4), 256, 0, stream>>>(C1, HID, fc2w, HID, C2, R_ROIS, HID, 256);
    bias_relu_k<<<2000, 256, 0, stream>>>(C2, fc2b, R_ROIS * HID / 4);
    gemm_heads<<<dim3(7, 32), 256, 0, stream>>>(C2, clsw, clsb, regw, regb, HEADS);
  }
  // softmax + decode + mask
  decode_k<<<500, 256, 0, stream>>>(HEADS, prop, imix, imsz, KEYS, BOXES);
  // exact top-1000 threshold per image
  hist_k<<<dim3(128, 2), 256, 0, stream>>>(KEYS, imix, SEL, HIST1, 1, 2048);
  find_k<<<2, 256, 0, stream>>>(HIST1, 2048, SEL, 1);
  hist_k<<<dim3(128, 2), 256, 0, stream>>>(KEYS, imix, SEL, HIST2, 2, 2048);
  find_k<<<2, 256, 0, stream>>>(HIST2, 2048, SEL, 2);
  hist_k<<<dim3(128, 2), 256, 0, stream>>>(KEYS, imix, SEL, HIST3, 3, 1024);
  find_k<<<2, 256, 0, stream>>>(HIST3, 1024, SEL, 3);
  // stable tie compaction + sort
  eqcount_k<<<dim3(NCHUNK, 2), 1024, 0, stream>>>(KEYS, imix, SEL, EQCNT);
  eqscan_k<<<2, 256, 0, stream>>>(EQCNT, EQOFF);
  emit_k<<<dim3(NCHUNK, 2), 1024, 0, stream>>>(KEYS, imix, SEL, EQOFF, CNTGT, CAND);
  sort_k<<<2, 512, 0, stream>>>(CAND, KEYS, imix, SORTED);
  // gather (fused) + NMS
  gather_k<<<2, 1024, 0, stream>>>(SORTED, BOXES, IDXK, SCK, BOXK, INVAL, OBK, AREA);
  nmsmat_k<<<dim3(63, 2), 256, 0, stream>>>(OBK, AREA, MROW);
  nmsscan_k<<<2, 64, 0, stream>>>(MROW, INVAL, IDXK, SCK, BOXK, out);
}